// Round 14
// baseline (1356.758 us; speedup 1.0000x reference)
//
#include <hip/hip_runtime.h>
#include <hip/hip_bf16.h>
#include <cstdint>
#include <cstddef>

typedef __attribute__((ext_vector_type(4))) float f32x4;
typedef __attribute__((ext_vector_type(16))) float f32x16;
typedef __attribute__((ext_vector_type(8))) short short8;
typedef unsigned short u16;
typedef __attribute__((ext_vector_type(8))) unsigned short u16x8;
typedef __attribute__((ext_vector_type(4))) unsigned short u16x4;

// ---------- helpers ----------
__device__ __forceinline__ u16 f2bf(float f) {
  union { float f; unsigned u; } v; v.f = f;
  unsigned r = v.u + 0x7FFFu + ((v.u >> 16) & 1u);
  return (u16)(r >> 16);
}
__device__ __forceinline__ float bf2f(u16 h) {
  union { unsigned u; float f; } v; v.u = ((unsigned)h) << 16;
  return v.f;
}
__device__ __forceinline__ void gload16(const u16* g, const u16* l) {
  __builtin_amdgcn_global_load_lds((const __attribute__((address_space(1))) void*)g,
                                   (__attribute__((address_space(3))) void*)l, 16, 0, 0);
}
__device__ __forceinline__ void fenced_barrier() {
  __builtin_amdgcn_sched_barrier(0);
  __builtin_amdgcn_s_barrier();
  __builtin_amdgcn_sched_barrier(0);
}

// ---------- prep: W2t = transpose(concat(Wq,Wk,Wv,tc_W)) as bf16 [3200][1024], zero rows 3104..3199 ----------
__global__ __launch_bounds__(256) void prep_w2t(
    const float* __restrict__ Wq, const float* __restrict__ Wk, const float* __restrict__ Wv,
    const float* __restrict__ tc, u16* __restrict__ W2t)
{
  __shared__ float t[32][33];
  const int tx = threadIdx.x, ty = threadIdx.y;   // 32 x 8
  const int k0 = blockIdx.x * 32, n0 = blockIdx.y * 32;
  const float* src = nullptr; int col = 0, sw = 0;
  if      (n0 < 1024) { src = Wq; col = n0;        sw = 1024; }
  else if (n0 < 2048) { src = Wk; col = n0 - 1024; sw = 1024; }
  else if (n0 < 3072) { src = Wv; col = n0 - 2048; sw = 1024; }
  else if (n0 < 3104) { src = tc; col = n0 - 3072; sw = 32;   }
  if (src) {
    #pragma unroll
    for (int r = 0; r < 4; r++) {
      int k = k0 + ty + r * 8;
      t[ty + r * 8][tx] = src[(size_t)k * sw + col + tx];
    }
  }
  __syncthreads();
  #pragma unroll
  for (int r = 0; r < 4; r++) {
    int n = n0 + ty + r * 8, k = k0 + tx;
    u16 v = src ? f2bf(t[tx][ty + r * 8]) : (u16)0;
    W2t[(size_t)n * 1024 + k] = v;
  }
}

// ---------- prep: generic fp32 [R][C] -> bf16 transposed [C][R], batched over z ----------
__global__ __launch_bounds__(256) void transpose_bf(
    const float* __restrict__ src, u16* __restrict__ dst, int R, int C)
{
  __shared__ float t[32][33];
  const int tx = threadIdx.x, ty = threadIdx.y;
  const size_t zoff = (size_t)blockIdx.z * R * C;
  src += zoff; dst += zoff;
  const int c0 = blockIdx.x * 32, r0 = blockIdx.y * 32;
  #pragma unroll
  for (int r = 0; r < 4; r++)
    t[ty + r * 8][tx] = src[(size_t)(r0 + ty + r * 8) * C + c0 + tx];
  __syncthreads();
  #pragma unroll
  for (int r = 0; r < 4; r++)
    dst[(size_t)(c0 + ty + r * 8) * R + r0 + tx] = f2bf(t[tx][ty + r * 8]);
}

// ---------- prep: x fp32 -> bf16 (linear) ----------
__global__ __launch_bounds__(256) void cvt_x(const float* __restrict__ x, u16* __restrict__ A2)
{
  size_t i = (size_t)blockIdx.x * 256 + threadIdx.x;
  f32x4 v = ((const f32x4*)x)[i];
  u16x4 o;
  #pragma unroll
  for (int j = 0; j < 4; j++) o[j] = f2bf(v[j]);
  ((u16x4*)A2)[i] = o;
}

// ---------- pipelined GEMM: 256x128 tile, BK=32, 8 waves (4Mx2N), ring-3, 72 KiB, 32x32x16 MFMA ----------
// FRAGMENT-RECORD LDS layout (lane-linear both sides, zero bank conflicts):
//   A-tile = 16 records; record (row32, cp) at (row32*2+cp)*512 u16: lane l holds
//     A[bm*256 + row32*32 + (l&31)][kt*32 + cp*16 + (l>>5)*8 .. +8]   (one b128 per lane)
//   B-tile = 8 records at 8192 + (col32*2+cp)*512, same per-lane form over Bt cols.
// Staging: 3 gloads/wave (2 A records + 1 B record), dest = record base + lane*16B (linear).
// Reads: frag = record base + lane*16B (lane-linear ds_read_b128). MFMA 32x32x16, ks = cp.
// Sync: per K-tile t: vmcnt(3); barrier; {8 ds_reads; STG(t+2); lgkm0; 8 MFMA} (R11-proven ring-3).
// MODE 0: QKV+flat scatter   MODE 3: logits (+alp_b+pos_bias, bf16)   MODE 4: final (+bo, f32)
template<int MODE>
__global__ __launch_bounds__(512, 4) void gemm_p(
    const u16* __restrict__ A, const u16* __restrict__ Bt, int K,
    void* __restrict__ o0, void* __restrict__ o1, void* __restrict__ o2, void* __restrict__ o3,
    const float* __restrict__ bias0, const float* __restrict__ bias1)
{
  __shared__ __align__(16) u16 lds[3][12288];   // [buf][ A:0..8191 | B:8192..12287 ] = 72 KiB
  const int tid = threadIdx.x;
  const int wid = tid >> 6, lane = tid & 63;
  const int wm = wid >> 1, wn = wid & 1;        // wave grid 4(M) x 2(N); per-wave out 64x64
  const int l31 = lane & 31, lh = lane >> 5;

  // XCD-bijective block swizzle (all grids have nwg%8==0)
  const int GX = gridDim.x;
  const int nwg = GX * (int)gridDim.y;
  const int lin = (int)blockIdx.y * GX + (int)blockIdx.x;
  const int swz = (lin & 7) * (nwg >> 3) + (lin >> 3);
  const int bn = swz % GX, bm = swz / GX;

  // per-lane global sources for the 3 records this wave stages each K-tile
  const u16* pA0 = A + (size_t)(bm * 256 + wid * 32 + l31) * K + 0 * 16 + lh * 8;   // record (wid, 0)
  const u16* pA1 = A + (size_t)(bm * 256 + wid * 32 + l31) * K + 1 * 16 + lh * 8;   // record (wid, 1)
  const u16* pB  = Bt + (size_t)(bn * 128 + (wid >> 1) * 32 + l31) * K + (wid & 1) * 16 + lh * 8;

  // lane-linear ds_read bases (u16 units)
  int aOff[2][2], bOff[2][2];
  #pragma unroll
  for (int fi = 0; fi < 2; fi++)
    #pragma unroll
    for (int ks = 0; ks < 2; ks++) {
      aOff[fi][ks] = (((wm * 2 + fi) * 2 + ks) * 512) + lane * 8;
      bOff[fi][ks] = 8192 + (((wn * 2 + fi) * 2 + ks) * 512) + lane * 8;
    }

  f32x16 acc[2][2];
  #pragma unroll
  for (int i = 0; i < 2; i++)
    #pragma unroll
    for (int j = 0; j < 2; j++)
      #pragma unroll
      for (int r = 0; r < 16; r++) acc[i][j][r] = 0.f;

  const int NT = K >> 5;

#define STG(buf, kt) do {                                                   \
    gload16(pA0 + (size_t)(kt) * 32, &lds[buf][(wid * 2 + 0) * 512]);       \
    gload16(pA1 + (size_t)(kt) * 32, &lds[buf][(wid * 2 + 1) * 512]);       \
    gload16(pB  + (size_t)(kt) * 32, &lds[buf][8192 + wid * 512]); } while (0)

  // prologue: K-tile 0 -> buf0, K-tile 1 -> buf1 (in flight)
  STG(0, 0); STG(1, 1);

  for (int t = 0; t < NT; t++) {
    const int rb = t % 3;
    const int wb = (t + 2) % 3;
    const bool more = (t + 2) < NT;

    if (t + 1 < NT) asm volatile("s_waitcnt vmcnt(3)" ::: "memory");
    else            asm volatile("s_waitcnt vmcnt(0)" ::: "memory");
    fenced_barrier();   // tile t published; orders upcoming STG(t+2) after prior reads of wb

    short8 af[2][2], bf[2][2];
    #pragma unroll
    for (int fi = 0; fi < 2; fi++)
      #pragma unroll
      for (int ks = 0; ks < 2; ks++) af[fi][ks] = *(const short8*)&lds[rb][aOff[fi][ks]];
    #pragma unroll
    for (int fj = 0; fj < 2; fj++)
      #pragma unroll
      for (int ks = 0; ks < 2; ks++) bf[fj][ks] = *(const short8*)&lds[rb][bOff[fj][ks]];
    if (more) STG(wb, t + 2);
    asm volatile("s_waitcnt lgkmcnt(0)" ::: "memory");
    __builtin_amdgcn_sched_barrier(0);
    __builtin_amdgcn_s_setprio(1);
    #pragma unroll
    for (int fi = 0; fi < 2; fi++)
      #pragma unroll
      for (int fj = 0; fj < 2; fj++)
        #pragma unroll
        for (int ks = 0; ks < 2; ks++)
          acc[fi][fj] = __builtin_amdgcn_mfma_f32_32x32x16_bf16(
              af[fi][ks], bf[fj][ks], acc[fi][fj], 0, 0, 0);
    __builtin_amdgcn_s_setprio(0);
  }
#undef STG

  // C/D layout (verified m74/m101, R13 refcheck-passed): col = lane&31, row = (r&3)+8*(r>>2)+4*(lane>>5)
  #pragma unroll
  for (int fi = 0; fi < 2; fi++) {
    #pragma unroll
    for (int fj = 0; fj < 2; fj++) {
      #pragma unroll
      for (int r = 0; r < 16; r++) {
        int gm = bm * 256 + wm * 64 + fi * 32 + (r & 3) + 8 * (r >> 2) + 4 * lh;
        int gn = bn * 128 + wn * 64 + fj * 32 + l31;
        float val = acc[fi][fj][r];
        if (MODE == 0) {
          int b = gm >> 6, s = gm & 63;
          if (gn < 3072) {
            int which = gn >> 10, hh = (gn >> 5) & 31, d = gn & 31;
            u16* dst = (which == 0) ? (u16*)o0 : (which == 1) ? (u16*)o1 : (u16*)o2;
            dst[(((size_t)b * 32 + hh) * 64 + s) * 32 + d] = f2bf(val);
          } else if (gn < 3104) {
            ((u16*)o3)[(size_t)b * 2048 + s * 32 + (gn - 3072)] = f2bf(val);
          }
        } else if (MODE == 3) {
          ((u16*)o0)[(size_t)gm * 4096 + gn] = f2bf(val + bias0[gn] + bias1[(gm & 31) * 4096 + gn]);
        } else {
          ((float*)o0)[(size_t)gm * 1024 + gn] = val + bias0[gn];
        }
      }
    }
  }
}

// ---------- small GEMM: 128x128 tile (modes 1,2) ----------
template<int MODE>
__global__ __launch_bounds__(256) void gemm_bt(
    const u16* __restrict__ A, const u16* __restrict__ Bt, int K,
    void* __restrict__ o0, const float* __restrict__ bias0)
{
  __shared__ __align__(16) u16 lA[128 * 32];
  __shared__ __align__(16) u16 lB[128 * 32];
  const int tid = threadIdx.x;
  const int wid = tid >> 6, lane = tid & 63;
  const int wm = wid >> 1, wn = wid & 1;
  const int bn = blockIdx.x, bm = blockIdx.y;
  if (MODE == 2) Bt += (size_t)blockIdx.z * 256 * 256;

  f32x4 acc[4][4];
  #pragma unroll
  for (int i = 0; i < 4; i++)
    #pragma unroll
    for (int j = 0; j < 4; j++)
      #pragma unroll
      for (int r = 0; r < 4; r++) acc[i][j][r] = 0.f;

  const u16* Arow = A + (size_t)(bm * 128) * K;
  const u16* Brow = Bt + (size_t)(bn * 128) * K;

  for (int k0 = 0; k0 < K; k0 += 32) {
    #pragma unroll
    for (int i = 0; i < 2; i++) {
      int c = wid * 128 + i * 64 + lane;
      int row = c >> 2, col = (c & 3) * 8;
      gload16(Arow + (size_t)row * K + k0 + col, &lA[(wid * 128 + i * 64) * 8]);
      gload16(Brow + (size_t)row * K + k0 + col, &lB[(wid * 128 + i * 64) * 8]);
    }
    __syncthreads();
    short8 af[4], bfr[4];
    #pragma unroll
    for (int f = 0; f < 4; f++) {
      af[f]  = *(const short8*)&lA[(wm * 64 + f * 16 + (lane & 15)) * 32 + (lane >> 4) * 8];
      bfr[f] = *(const short8*)&lB[(wn * 64 + f * 16 + (lane & 15)) * 32 + (lane >> 4) * 8];
    }
    #pragma unroll
    for (int fm = 0; fm < 4; fm++)
      #pragma unroll
      for (int fn = 0; fn < 4; fn++)
        acc[fm][fn] = __builtin_amdgcn_mfma_f32_16x16x32_bf16(af[fm], bfr[fn], acc[fm][fn], 0, 0, 0);
    __syncthreads();
  }

  const int lr = lane >> 4, lc = lane & 15;
  #pragma unroll
  for (int fm = 0; fm < 4; fm++) {
    #pragma unroll
    for (int fn = 0; fn < 4; fn++) {
      #pragma unroll
      for (int r = 0; r < 4; r++) {
        int gm = bm * 128 + wm * 64 + fm * 16 + lr * 4 + r;
        int gn = bn * 128 + wn * 64 + fn * 16 + lc;
        float val = acc[fm][fn][r];
        if (MODE == 1) {
          float v = val + bias0[gn];
          ((float*)o0)[(size_t)gm * 256 + gn] = v > 0.f ? v : 0.f;
        } else if (MODE == 2) {
          int h = blockIdx.z;
          ((u16*)o0)[((size_t)gm * 32 + h) * 256 + gn] = f2bf(val + bias0[h * 256 + gn]);
        }
      }
    }
  }
}

// ---------- LayerNorm over 256 cols ----------
__global__ __launch_bounds__(256) void ln_kernel(
    const float* __restrict__ pv, const float* __restrict__ g, const float* __restrict__ b2,
    u16* __restrict__ out)
{
  __shared__ float red[256];
  const int bi = blockIdx.x, t = threadIdx.x;
  float v = pv[(size_t)bi * 256 + t];
  red[t] = v; __syncthreads();
  #pragma unroll
  for (int o = 128; o > 0; o >>= 1) { if (t < o) red[t] += red[t + o]; __syncthreads(); }
  float mu = red[0] * (1.f / 256.f);
  __syncthreads();
  float dv = v - mu;
  red[t] = dv * dv; __syncthreads();
  #pragma unroll
  for (int o = 128; o > 0; o >>= 1) { if (t < o) red[t] += red[t + o]; __syncthreads(); }
  float var = red[0] * (1.f / 256.f);
  float rs = rsqrtf(var + 1e-5f);
  out[(size_t)bi * 256 + t] = f2bf(dv * rs * g[t] + b2[t]);
}

// ---------- attention core, MFMA version: one wave per (b,h) ----------
__global__ __launch_bounds__(64) void attn_mfma(
    const u16* __restrict__ qb, const u16* __restrict__ kb, const u16* __restrict__ vb,
    const u16* __restrict__ lg, u16* __restrict__ aout)
{
  __shared__ __align__(16) u16 vT[32 * 64];
  __shared__ __align__(16) u16 Pl[64 * 64];
  const int bid = blockIdx.x;
  const int lane = threadIdx.x;
  const int g = lane >> 4, l15 = lane & 15;
  const size_t base = (size_t)bid * 2048;

  {
    const u16* vrow = vb + base + lane * 32;
    u16x8 vv[4];
    #pragma unroll
    for (int c = 0; c < 4; c++) vv[c] = *(const u16x8*)(vrow + c * 8);
    #pragma unroll
    for (int d = 0; d < 32; d++)
      vT[d * 64 + (lane ^ ((d & 7) << 3))] = vv[d >> 3][d & 7];
  }

  short8 qf[4], kf[4];
  #pragma unroll
  for (int t = 0; t < 4; t++) {
    qf[t] = *(const short8*)(qb + base + (size_t)(t * 16 + l15) * 32 + g * 8);
    kf[t] = *(const short8*)(kb + base + (size_t)(t * 16 + l15) * 32 + g * 8);
  }

  f32x4 s[4][4];
  #pragma unroll
  for (int tm = 0; tm < 4; tm++)
    #pragma unroll
    for (int tn = 0; tn < 4; tn++)
      #pragma unroll
      for (int r = 0; r < 4; r++) s[tm][tn][r] = 0.f;
  #pragma unroll
  for (int tm = 0; tm < 4; tm++)
    #pragma unroll
    for (int tn = 0; tn < 4; tn++)
      s[tm][tn] = __builtin_amdgcn_mfma_f32_16x16x32_bf16(kf[tm], qf[tn], s[tm][tn], 0, 0, 0);

  const float scale = 0.17677669529663687f;
  float inv4[4];
  const u16* lbase = lg + (size_t)bid * 4096;
  #pragma unroll
  for (int tn = 0; tn < 4; tn++) {
    const int q = tn * 16 + l15;
    float mx = -1e30f;
    #pragma unroll
    for (int tm = 0; tm < 4; tm++) {
      u16x4 u = *(const u16x4*)(lbase + (size_t)q * 64 + tm * 16 + g * 4);
      #pragma unroll
      for (int r = 0; r < 4; r++) {
        s[tm][tn][r] = s[tm][tn][r] * scale + bf2f(u[r]);
        mx = fmaxf(mx, s[tm][tn][r]);
      }
    }
    mx = fmaxf(mx, __shfl_xor(mx, 16));
    mx = fmaxf(mx, __shfl_xor(mx, 32));
    float sm = 0.f;
    #pragma unroll
    for (int tm = 0; tm < 4; tm++)
      #pragma unroll
      for (int r = 0; r < 4; r++) {
        float e = __expf(s[tm][tn][r] - mx);
        s[tm][tn][r] = e;
        sm += e;
      }
    sm += __shfl_xor(sm, 16);
    sm += __shfl_xor(sm, 32);
    inv4[tn] = 1.f / sm;
    #pragma unroll
    for (int tm = 0; tm < 4; tm++) {
      u16x4 p;
      #pragma unroll
      for (int r = 0; r < 4; r++) p[r] = f2bf(s[tm][tn][r]);
      *(u16x4*)&Pl[q * 64 + ((tm * 16 + g * 4) ^ ((q & 7) << 3))] = p;
    }
  }
  __syncthreads();

  f32x4 o[2][4];
  #pragma unroll
  for (int md = 0; md < 2; md++)
    #pragma unroll
    for (int tn = 0; tn < 4; tn++)
      #pragma unroll
      for (int r = 0; r < 4; r++) o[md][tn][r] = 0.f;
  #pragma unroll
  for (int ks = 0; ks < 2; ks++) {
    short8 vf2[2], pf[4];
    #pragma unroll
    for (int md = 0; md < 2; md++)
      vf2[md] = *(const short8*)&vT[(md * 16 + l15) * 64 + ((ks * 32 + g * 8) ^ ((l15 & 7) << 3))];
    #pragma unroll
    for (int tn = 0; tn < 4; tn++)
      pf[tn] = *(const short8*)&Pl[(tn * 16 + l15) * 64 + ((ks * 32 + g * 8) ^ ((l15 & 7) << 3))];
    #pragma unroll
    for (int md = 0; md < 2; md++)
      #pragma unroll
      for (int tn = 0; tn < 4; tn++)
        o[md][tn] = __builtin_amdgcn_mfma_f32_16x16x32_bf16(vf2[md], pf[tn], o[md][tn], 0, 0, 0);
  }

  const int b = bid >> 5, h = bid & 31;
  #pragma unroll
  for (int md = 0; md < 2; md++) {
    #pragma unroll
    for (int tn = 0; tn < 4; tn++) {
      const int q = tn * 16 + l15, d0 = md * 16 + g * 4;
      u16x4 u;
      #pragma unroll
      for (int r = 0; r < 4; r++) u[r] = f2bf(o[md][tn][r] * inv4[tn]);
      *(u16x4*)(aout + ((size_t)(b * 64 + q)) * 1024 + h * 32 + d0) = u;
    }
  }
}

// ---------- launch ----------
extern "C" void kernel_launch(void* const* d_in, const int* in_sizes, int n_in,
                              void* d_out, int out_size, void* d_ws, size_t ws_size,
                              hipStream_t stream) {
  const float* x       = (const float*)d_in[0];
  const float* Wq      = (const float*)d_in[1];
  const float* Wk      = (const float*)d_in[2];
  const float* Wv      = (const float*)d_in[3];
  const float* Wo      = (const float*)d_in[4];
  const float* bo      = (const float*)d_in[5];
  const float* pos_b   = (const float*)d_in[6];
  const float* tc_W    = (const float*)d_in[7];
  const float* pc_W    = (const float*)d_in[8];
  const float* pc_b    = (const float*)d_in[9];
  const float* ln_g    = (const float*)d_in[10];
  const float* ln_b    = (const float*)d_in[11];
  const float* hp_W    = (const float*)d_in[12];
  const float* hp_b    = (const float*)d_in[13];
  const float* alp_W   = (const float*)d_in[14];
  const float* alp_b   = (const float*)d_in[15];
  float* out = (float*)d_out;

  char* w = (char*)d_ws;
  u16* A2     = (u16*)w;              // 134 MB bf16 x, dead after gemm_p<0>
  u16* logits = (u16*)w;              w += 268435456;   // logits aliases A2 region
  u16* qb     = (u16*)w;              w += 134217728;
  u16* kb     = (u16*)w;              w += 134217728;
  u16* vb     = (u16*)w;              w += 134217728;
  u16* aout   = (u16*)w;              w += 134217728;
  u16* W2t    = (u16*)w;              w += (size_t)3200 * 1024 * 2;
  u16* pcWt   = (u16*)w;              w += (size_t)256 * 2048 * 2;
  u16* hpWt   = (u16*)w;              w += (size_t)32 * 256 * 256 * 2;
  u16* alpWt  = (u16*)w;              w += (size_t)4096 * 256 * 2;
  u16* WoT    = (u16*)w;              w += (size_t)1024 * 1024 * 2;
  u16* flatb  = (u16*)w;              w += (size_t)1024 * 2048 * 2;
  float* pvtmp= (float*)w;            w += (size_t)1024 * 256 * 4;
  u16* pvb    = (u16*)w;              w += (size_t)1024 * 256 * 2;
  u16* hvb    = (u16*)w;              w += (size_t)32768 * 256 * 2;

  prep_w2t    <<<dim3(32, 100),    dim3(32, 8), 0, stream>>>(Wq, Wk, Wv, tc_W, W2t);
  transpose_bf<<<dim3(8, 64, 1),   dim3(32, 8), 0, stream>>>(pc_W, pcWt, 2048, 256);
  transpose_bf<<<dim3(8, 8, 32),   dim3(32, 8), 0, stream>>>(hp_W, hpWt, 256, 256);
  transpose_bf<<<dim3(128, 8, 1),  dim3(32, 8), 0, stream>>>(alp_W, alpWt, 256, 4096);
  transpose_bf<<<dim3(32, 32, 1),  dim3(32, 8), 0, stream>>>(Wo, WoT, 1024, 1024);
  cvt_x       <<<65536, 256, 0, stream>>>(x, A2);

  gemm_p<0> <<<dim3(25, 256),    512, 0, stream>>>(A2, W2t, 1024, qb, kb, vb, flatb, nullptr, nullptr);
  gemm_bt<1><<<dim3(2, 8),       256, 0, stream>>>(flatb, pcWt, 2048, pvtmp, pc_b);
  ln_kernel <<<1024, 256, 0, stream>>>(pvtmp, ln_g, ln_b, pvb);
  gemm_bt<2><<<dim3(2, 8, 32),   256, 0, stream>>>(pvb, hpWt, 256, hvb, hp_b);
  gemm_p<3> <<<dim3(32, 128),    512, 0, stream>>>(hvb, alpWt, 256, logits, nullptr, nullptr, nullptr, alp_b, pos_b);
  attn_mfma <<<32768, 64, 0, stream>>>(qb, kb, vb, logits, aout);
  gemm_p<4> <<<dim3(8, 256),     512, 0, stream>>>(aout, WoT, 1024, out, nullptr, nullptr, nullptr, bo, nullptr);
}

// Round 15
// 1086.148 us; speedup vs baseline: 1.2491x; 1.2491x over previous
//
#include <hip/hip_runtime.h>
#include <hip/hip_bf16.h>
#include <cstdint>
#include <cstddef>

typedef __attribute__((ext_vector_type(4))) float f32x4;
typedef __attribute__((ext_vector_type(8))) short short8;
typedef unsigned short u16;
typedef __attribute__((ext_vector_type(8))) unsigned short u16x8;
typedef __attribute__((ext_vector_type(4))) unsigned short u16x4;

// ---------- helpers ----------
__device__ __forceinline__ u16 f2bf(float f) {
  union { float f; unsigned u; } v; v.f = f;
  unsigned r = v.u + 0x7FFFu + ((v.u >> 16) & 1u);
  return (u16)(r >> 16);
}
__device__ __forceinline__ float bf2f(u16 h) {
  union { unsigned u; float f; } v; v.u = ((unsigned)h) << 16;
  return v.f;
}
__device__ __forceinline__ void gload16(const u16* g, const u16* l) {
  __builtin_amdgcn_global_load_lds((const __attribute__((address_space(1))) void*)g,
                                   (__attribute__((address_space(3))) void*)l, 16, 0, 0);
}
__device__ __forceinline__ void fenced_barrier() {
  __builtin_amdgcn_sched_barrier(0);
  __builtin_amdgcn_s_barrier();
  __builtin_amdgcn_sched_barrier(0);
}

// ---------- prep: W2t = transpose(concat(Wq,Wk,Wv,tc_W)) as bf16 [3200][1024], zero rows 3104..3199 ----------
__global__ __launch_bounds__(256) void prep_w2t(
    const float* __restrict__ Wq, const float* __restrict__ Wk, const float* __restrict__ Wv,
    const float* __restrict__ tc, u16* __restrict__ W2t)
{
  __shared__ float t[32][33];
  const int tx = threadIdx.x, ty = threadIdx.y;   // 32 x 8
  const int k0 = blockIdx.x * 32, n0 = blockIdx.y * 32;
  const float* src = nullptr; int col = 0, sw = 0;
  if      (n0 < 1024) { src = Wq; col = n0;        sw = 1024; }
  else if (n0 < 2048) { src = Wk; col = n0 - 1024; sw = 1024; }
  else if (n0 < 3072) { src = Wv; col = n0 - 2048; sw = 1024; }
  else if (n0 < 3104) { src = tc; col = n0 - 3072; sw = 32;   }
  if (src) {
    #pragma unroll
    for (int r = 0; r < 4; r++) {
      int k = k0 + ty + r * 8;
      t[ty + r * 8][tx] = src[(size_t)k * sw + col + tx];
    }
  }
  __syncthreads();
  #pragma unroll
  for (int r = 0; r < 4; r++) {
    int n = n0 + ty + r * 8, k = k0 + tx;
    u16 v = src ? f2bf(t[tx][ty + r * 8]) : (u16)0;
    W2t[(size_t)n * 1024 + k] = v;
  }
}

// ---------- prep: generic fp32 [R][C] -> bf16 transposed [C][R], batched over z ----------
__global__ __launch_bounds__(256) void transpose_bf(
    const float* __restrict__ src, u16* __restrict__ dst, int R, int C)
{
  __shared__ float t[32][33];
  const int tx = threadIdx.x, ty = threadIdx.y;
  const size_t zoff = (size_t)blockIdx.z * R * C;
  src += zoff; dst += zoff;
  const int c0 = blockIdx.x * 32, r0 = blockIdx.y * 32;
  #pragma unroll
  for (int r = 0; r < 4; r++)
    t[ty + r * 8][tx] = src[(size_t)(r0 + ty + r * 8) * C + c0 + tx];
  __syncthreads();
  #pragma unroll
  for (int r = 0; r < 4; r++)
    dst[(size_t)(c0 + ty + r * 8) * R + r0 + tx] = f2bf(t[tx][ty + r * 8]);
}

// ---------- prep: x fp32 -> bf16 (linear) ----------
__global__ __launch_bounds__(256) void cvt_x(const float* __restrict__ x, u16* __restrict__ A2)
{
  size_t i = (size_t)blockIdx.x * 256 + threadIdx.x;
  f32x4 v = ((const f32x4*)x)[i];
  u16x4 o;
  #pragma unroll
  for (int j = 0; j < 4; j++) o[j] = f2bf(v[j]);
  ((u16x4*)A2)[i] = o;
}

// ---------- pipelined GEMM (R11-proven): 256x128 tile, BK=32, 8 waves (4Mx2N), ring-3, 72 KiB ----------
// Unrolled x3 with STATIC ring indices (K compile-time; NT-2 % 3 == 0 for K in {1024, 256}).
// A fold: [128 R][8 chunks of 8 u16]: global row = bm*256 + hb*128 + R, stored chunk = (hb*4+sg) ^ (R&7).
// B fold: [64 R][8 chunks]: global col = bn*128 + hb*64 + R, stored = (hb*4+sg) ^ (R&7).
// Per K-tile t: vmcnt(3) [tile t landed, t+1 in flight]; barrier;
//               {8 ds_reads; STG(t+2) (3 gloads); lgkm0; 16 MFMA 16x16x32}.
// Safety (ring-3, 1 barrier): reads of a buffer are lgkm-drained before the barrier that
// precedes any re-staging into it (issue-after-barrier => land-after-reads).
// MODE 0: QKV+flat scatter   MODE 3: logits (+alp_b+pos_bias, bf16)   MODE 4: final (+bo, f32)
template<int MODE, int K>
__global__ __launch_bounds__(512, 4) void gemm_p(
    const u16* __restrict__ A, const u16* __restrict__ Bt,
    void* __restrict__ o0, void* __restrict__ o1, void* __restrict__ o2, void* __restrict__ o3,
    const float* __restrict__ bias0, const float* __restrict__ bias1)
{
  __shared__ __align__(16) u16 lds[3][12288];   // [buf][ A:0..8191 | B:8192..12287 ] = 72 KiB
  const int tid = threadIdx.x;
  const int wid = tid >> 6, lane = tid & 63;
  const int wm = wid >> 1, wn = wid & 1;        // wave grid 4(M) x 2(N); per-wave out 64x64
  const int g = lane >> 4, l15 = lane & 15;

  // XCD-bijective block swizzle (all grids have nwg%8==0)
  const int GX = gridDim.x;
  const int nwg = GX * (int)gridDim.y;
  const int lin = (int)blockIdx.y * GX + (int)blockIdx.x;
  const int swz = (lin & 7) * (nwg >> 3) + (lin >> 3);
  const int bn = swz % GX, bm = swz / GX;

  // staging lane decomposition (proven): one gload = 8 folded rows; lane -> (row lR, stored chunk lane&7)
  const int lR = lane >> 3;
  const int logi = (lane & 7) ^ lR;             // logical chunk = stored ^ (R&7)
  const int shb = logi >> 2;                    // row-half select (x128 for A, x64 for B)
  const int sg = logi & 3;                      // k-subchunk (8 u16) within BK=32

  const u16* pA0 = A + (size_t)(bm * 256 + shb * 128 + (wid * 2 + 0) * 8 + lR) * K + sg * 8;
  const u16* pA1 = A + (size_t)(bm * 256 + shb * 128 + (wid * 2 + 1) * 8 + lR) * K + sg * 8;
  const u16* pB  = Bt + (size_t)(bn * 128 + shb * 64 + wid * 8 + lR) * K + sg * 8;

  // swizzled ds_read bases (u16 units): A folded row = (wm&1)*64 + f*16 + l15, hb = wm>>1
  const int aRd = ((wm & 1) * 64 + l15) * 64 + ((((wm >> 1) << 2) | g) ^ (l15 & 7)) * 8;
  const int bRd = 8192 + l15 * 64 + ((((wn << 2) | g) ^ (l15 & 7)) * 8);

  f32x4 acc[4][4];
  #pragma unroll
  for (int i = 0; i < 4; i++)
    #pragma unroll
    for (int j = 0; j < 4; j++)
      #pragma unroll
      for (int r = 0; r < 4; r++) acc[i][j][r] = 0.f;

  constexpr int NT = K >> 5;
  static_assert((NT - 2) % 3 == 0, "unroll-3 requires NT-2 divisible by 3");

#define STG(buf, kt) do {                                                   \
    gload16(pA0 + (size_t)(kt) * 32, &lds[buf][(wid * 2 + 0) * 512]);       \
    gload16(pA1 + (size_t)(kt) * 32, &lds[buf][(wid * 2 + 1) * 512]);       \
    gload16(pB  + (size_t)(kt) * 32, &lds[buf][8192 + wid * 512]); } while (0)

#define ITER(T_, RB_, WB_, DO_STG, VM) do {                                 \
    asm volatile("s_waitcnt vmcnt(" #VM ")" ::: "memory");                  \
    fenced_barrier();                                                       \
    short8 af[4], bfr[4];                                                   \
    _Pragma("unroll")                                                       \
    for (int f_ = 0; f_ < 4; f_++)                                          \
      af[f_] = *(const short8*)&lds[RB_][aRd + f_ * 1024];                  \
    _Pragma("unroll")                                                       \
    for (int n_ = 0; n_ < 4; n_++)                                          \
      bfr[n_] = *(const short8*)&lds[RB_][bRd + n_ * 1024];                 \
    if (DO_STG) STG(WB_, (T_) + 2);                                         \
    asm volatile("s_waitcnt lgkmcnt(0)" ::: "memory");                      \
    __builtin_amdgcn_sched_barrier(0);                                      \
    __builtin_amdgcn_s_setprio(1);                                          \
    _Pragma("unroll")                                                       \
    for (int f_ = 0; f_ < 4; f_++)                                          \
      _Pragma("unroll")                                                     \
      for (int n_ = 0; n_ < 4; n_++)                                        \
        acc[f_][n_] = __builtin_amdgcn_mfma_f32_16x16x32_bf16(              \
            af[f_], bfr[n_], acc[f_][n_], 0, 0, 0);                         \
    __builtin_amdgcn_s_setprio(0);                                          \
  } while (0)

  // prologue: K-tile 0 -> buf0, K-tile 1 -> buf1 (in flight)
  STG(0, 0); STG(1, 1);

  for (int tb = 0; tb < NT - 2; tb += 3) {
    ITER(tb + 0, 0, 2, true, 3);
    ITER(tb + 1, 1, 0, true, 3);
    ITER(tb + 2, 2, 1, true, 3);
  }
  // tail: t = NT-2 (rb 0), t = NT-1 (rb 1); no staging
  ITER(NT - 2, 0, 0, false, 3);
  ITER(NT - 1, 1, 0, false, 0);
#undef ITER
#undef STG

  const int lr = lane >> 4, lc = lane & 15;
  #pragma unroll
  for (int fm = 0; fm < 4; fm++) {
    #pragma unroll
    for (int fn = 0; fn < 4; fn++) {
      #pragma unroll
      for (int r = 0; r < 4; r++) {
        int gm = bm * 256 + wm * 64 + fm * 16 + lr * 4 + r;
        int gn = bn * 128 + wn * 64 + fn * 16 + lc;
        float val = acc[fm][fn][r];
        if (MODE == 0) {
          int b = gm >> 6, s = gm & 63;
          if (gn < 3072) {
            int which = gn >> 10, hh = (gn >> 5) & 31, d = gn & 31;
            u16* dst = (which == 0) ? (u16*)o0 : (which == 1) ? (u16*)o1 : (u16*)o2;
            dst[(((size_t)b * 32 + hh) * 64 + s) * 32 + d] = f2bf(val);
          } else if (gn < 3104) {
            ((u16*)o3)[(size_t)b * 2048 + s * 32 + (gn - 3072)] = f2bf(val);
          }
        } else if (MODE == 3) {
          ((u16*)o0)[(size_t)gm * 4096 + gn] = f2bf(val + bias0[gn] + bias1[(gm & 31) * 4096 + gn]);
        } else {
          ((float*)o0)[(size_t)gm * 1024 + gn] = val + bias0[gn];
        }
      }
    }
  }
}

// ---------- small GEMM: 128x128 tile (modes 1,2) ----------
template<int MODE>
__global__ __launch_bounds__(256) void gemm_bt(
    const u16* __restrict__ A, const u16* __restrict__ Bt, int K,
    void* __restrict__ o0, const float* __restrict__ bias0)
{
  __shared__ __align__(16) u16 lA[128 * 32];
  __shared__ __align__(16) u16 lB[128 * 32];
  const int tid = threadIdx.x;
  const int wid = tid >> 6, lane = tid & 63;
  const int wm = wid >> 1, wn = wid & 1;
  const int bn = blockIdx.x, bm = blockIdx.y;
  if (MODE == 2) Bt += (size_t)blockIdx.z * 256 * 256;

  f32x4 acc[4][4];
  #pragma unroll
  for (int i = 0; i < 4; i++)
    #pragma unroll
    for (int j = 0; j < 4; j++)
      #pragma unroll
      for (int r = 0; r < 4; r++) acc[i][j][r] = 0.f;

  const u16* Arow = A + (size_t)(bm * 128) * K;
  const u16* Brow = Bt + (size_t)(bn * 128) * K;

  for (int k0 = 0; k0 < K; k0 += 32) {
    #pragma unroll
    for (int i = 0; i < 2; i++) {
      int c = wid * 128 + i * 64 + lane;
      int row = c >> 2, col = (c & 3) * 8;
      gload16(Arow + (size_t)row * K + k0 + col, &lA[(wid * 128 + i * 64) * 8]);
      gload16(Brow + (size_t)row * K + k0 + col, &lB[(wid * 128 + i * 64) * 8]);
    }
    __syncthreads();
    short8 af[4], bfr[4];
    #pragma unroll
    for (int f = 0; f < 4; f++) {
      af[f]  = *(const short8*)&lA[(wm * 64 + f * 16 + (lane & 15)) * 32 + (lane >> 4) * 8];
      bfr[f] = *(const short8*)&lB[(wn * 64 + f * 16 + (lane & 15)) * 32 + (lane >> 4) * 8];
    }
    #pragma unroll
    for (int fm = 0; fm < 4; fm++)
      #pragma unroll
      for (int fn = 0; fn < 4; fn++)
        acc[fm][fn] = __builtin_amdgcn_mfma_f32_16x16x32_bf16(af[fm], bfr[fn], acc[fm][fn], 0, 0, 0);
    __syncthreads();
  }

  const int lr = lane >> 4, lc = lane & 15;
  #pragma unroll
  for (int fm = 0; fm < 4; fm++) {
    #pragma unroll
    for (int fn = 0; fn < 4; fn++) {
      #pragma unroll
      for (int r = 0; r < 4; r++) {
        int gm = bm * 128 + wm * 64 + fm * 16 + lr * 4 + r;
        int gn = bn * 128 + wn * 64 + fn * 16 + lc;
        float val = acc[fm][fn][r];
        if (MODE == 1) {
          float v = val + bias0[gn];
          ((float*)o0)[(size_t)gm * 256 + gn] = v > 0.f ? v : 0.f;
        } else if (MODE == 2) {
          int h = blockIdx.z;
          ((u16*)o0)[((size_t)gm * 32 + h) * 256 + gn] = f2bf(val + bias0[h * 256 + gn]);
        }
      }
    }
  }
}

// ---------- LayerNorm over 256 cols ----------
__global__ __launch_bounds__(256) void ln_kernel(
    const float* __restrict__ pv, const float* __restrict__ g, const float* __restrict__ b2,
    u16* __restrict__ out)
{
  __shared__ float red[256];
  const int bi = blockIdx.x, t = threadIdx.x;
  float v = pv[(size_t)bi * 256 + t];
  red[t] = v; __syncthreads();
  #pragma unroll
  for (int o = 128; o > 0; o >>= 1) { if (t < o) red[t] += red[t + o]; __syncthreads(); }
  float mu = red[0] * (1.f / 256.f);
  __syncthreads();
  float dv = v - mu;
  red[t] = dv * dv; __syncthreads();
  #pragma unroll
  for (int o = 128; o > 0; o >>= 1) { if (t < o) red[t] += red[t + o]; __syncthreads(); }
  float var = red[0] * (1.f / 256.f);
  float rs = rsqrtf(var + 1e-5f);
  out[(size_t)bi * 256 + t] = f2bf(dv * rs * g[t] + b2[t]);
}

// ---------- attention core, MFMA version: one wave per (b,h) ----------
__global__ __launch_bounds__(64) void attn_mfma(
    const u16* __restrict__ qb, const u16* __restrict__ kb, const u16* __restrict__ vb,
    const u16* __restrict__ lg, u16* __restrict__ aout)
{
  __shared__ __align__(16) u16 vT[32 * 64];
  __shared__ __align__(16) u16 Pl[64 * 64];
  const int bid = blockIdx.x;
  const int lane = threadIdx.x;
  const int g = lane >> 4, l15 = lane & 15;
  const size_t base = (size_t)bid * 2048;

  {
    const u16* vrow = vb + base + lane * 32;
    u16x8 vv[4];
    #pragma unroll
    for (int c = 0; c < 4; c++) vv[c] = *(const u16x8*)(vrow + c * 8);
    #pragma unroll
    for (int d = 0; d < 32; d++)
      vT[d * 64 + (lane ^ ((d & 7) << 3))] = vv[d >> 3][d & 7];
  }

  short8 qf[4], kf[4];
  #pragma unroll
  for (int t = 0; t < 4; t++) {
    qf[t] = *(const short8*)(qb + base + (size_t)(t * 16 + l15) * 32 + g * 8);
    kf[t] = *(const short8*)(kb + base + (size_t)(t * 16 + l15) * 32 + g * 8);
  }

  f32x4 s[4][4];
  #pragma unroll
  for (int tm = 0; tm < 4; tm++)
    #pragma unroll
    for (int tn = 0; tn < 4; tn++)
      #pragma unroll
      for (int r = 0; r < 4; r++) s[tm][tn][r] = 0.f;
  #pragma unroll
  for (int tm = 0; tm < 4; tm++)
    #pragma unroll
    for (int tn = 0; tn < 4; tn++)
      s[tm][tn] = __builtin_amdgcn_mfma_f32_16x16x32_bf16(kf[tm], qf[tn], s[tm][tn], 0, 0, 0);

  const float scale = 0.17677669529663687f;
  float inv4[4];
  const u16* lbase = lg + (size_t)bid * 4096;
  #pragma unroll
  for (int tn = 0; tn < 4; tn++) {
    const int q = tn * 16 + l15;
    float mx = -1e30f;
    #pragma unroll
    for (int tm = 0; tm < 4; tm++) {
      u16x4 u = *(const u16x4*)(lbase + (size_t)q * 64 + tm * 16 + g * 4);
      #pragma unroll
      for (int r = 0; r < 4; r++) {
        s[tm][tn][r] = s[tm][tn][r] * scale + bf2f(u[r]);
        mx = fmaxf(mx, s[tm][tn][r]);
      }
    }
    mx = fmaxf(mx, __shfl_xor(mx, 16));
    mx = fmaxf(mx, __shfl_xor(mx, 32));
    float sm = 0.f;
    #pragma unroll
    for (int tm = 0; tm < 4; tm++)
      #pragma unroll
      for (int r = 0; r < 4; r++) {
        float e = __expf(s[tm][tn][r] - mx);
        s[tm][tn][r] = e;
        sm += e;
      }
    sm += __shfl_xor(sm, 16);
    sm += __shfl_xor(sm, 32);
    inv4[tn] = 1.f / sm;
    #pragma unroll
    for (int tm = 0; tm < 4; tm++) {
      u16x4 p;
      #pragma unroll
      for (int r = 0; r < 4; r++) p[r] = f2bf(s[tm][tn][r]);
      *(u16x4*)&Pl[q * 64 + ((tm * 16 + g * 4) ^ ((q & 7) << 3))] = p;
    }
  }
  __syncthreads();

  f32x4 o[2][4];
  #pragma unroll
  for (int md = 0; md < 2; md++)
    #pragma unroll
    for (int tn = 0; tn < 4; tn++)
      #pragma unroll
      for (int r = 0; r < 4; r++) o[md][tn][r] = 0.f;
  #pragma unroll
  for (int ks = 0; ks < 2; ks++) {
    short8 vf2[2], pf[4];
    #pragma unroll
    for (int md = 0; md < 2; md++)
      vf2[md] = *(const short8*)&vT[(md * 16 + l15) * 64 + ((ks * 32 + g * 8) ^ ((l15 & 7) << 3))];
    #pragma unroll
    for (int tn = 0; tn < 4; tn++)
      pf[tn] = *(const short8*)&Pl[(tn * 16 + l15) * 64 + ((ks * 32 + g * 8) ^ ((l15 & 7) << 3))];
    #pragma unroll
    for (int md = 0; md < 2; md++)
      #pragma unroll
      for (int tn = 0; tn < 4; tn++)
        o[md][tn] = __builtin_amdgcn_mfma_f32_16x16x32_bf16(vf2[md], pf[tn], o[md][tn], 0, 0, 0);
  }

  const int b = bid >> 5, h = bid & 31;
  #pragma unroll
  for (int md = 0; md < 2; md++) {
    #pragma unroll
    for (int tn = 0; tn < 4; tn++) {
      const int q = tn * 16 + l15, d0 = md * 16 + g * 4;
      u16x4 u;
      #pragma unroll
      for (int r = 0; r < 4; r++) u[r] = f2bf(o[md][tn][r] * inv4[tn]);
      *(u16x4*)(aout + ((size_t)(b * 64 + q)) * 1024 + h * 32 + d0) = u;
    }
  }
}

// ---------- launch ----------
extern "C" void kernel_launch(void* const* d_in, const int* in_sizes, int n_in,
                              void* d_out, int out_size, void* d_ws, size_t ws_size,
                              hipStream_t stream) {
  const float* x       = (const float*)d_in[0];
  const float* Wq      = (const float*)d_in[1];
  const float* Wk      = (const float*)d_in[2];
  const float* Wv      = (const float*)d_in[3];
  const float* Wo      = (const float*)d_in[4];
  const float* bo      = (const float*)d_in[5];
  const float* pos_b   = (const float*)d_in[6];
  const float* tc_W    = (const float*)d_in[7];
  const float* pc_W    = (const float*)d_in[8];
  const float* pc_b    = (const float*)d_in[9];
  const float* ln_g    = (const float*)d_in[10];
  const float* ln_b    = (const float*)d_in[11];
  const float* hp_W    = (const float*)d_in[12];
  const float* hp_b    = (const float*)d_in[13];
  const float* alp_W   = (const float*)d_in[14];
  const float* alp_b   = (const float*)d_in[15];
  float* out = (float*)d_out;

  char* w = (char*)d_ws;
  u16* A2     = (u16*)w;              // 134 MB bf16 x, dead after gemm_p<0>
  u16* logits = (u16*)w;              w += 268435456;   // logits aliases A2 region
  u16* qb     = (u16*)w;              w += 134217728;
  u16* kb     = (u16*)w;              w += 134217728;
  u16* vb     = (u16*)w;              w += 134217728;
  u16* aout   = (u16*)w;              w += 134217728;
  u16* W2t    = (u16*)w;              w += (size_t)3200 * 1024 * 2;
  u16* pcWt   = (u16*)w;              w += (size_t)256 * 2048 * 2;
  u16* hpWt   = (u16*)w;              w += (size_t)32 * 256 * 256 * 2;
  u16* alpWt  = (u16*)w;              w += (size_t)4096 * 256 * 2;
  u16* WoT    = (u16*)w;              w += (size_t)1024 * 1024 * 2;
  u16* flatb  = (u16*)w;              w += (size_t)1024 * 2048 * 2;
  float* pvtmp= (float*)w;            w += (size_t)1024 * 256 * 4;
  u16* pvb    = (u16*)w;              w += (size_t)1024 * 256 * 2;
  u16* hvb    = (u16*)w;              w += (size_t)32768 * 256 * 2;

  prep_w2t    <<<dim3(32, 100),    dim3(32, 8), 0, stream>>>(Wq, Wk, Wv, tc_W, W2t);
  transpose_bf<<<dim3(8, 64, 1),   dim3(32, 8), 0, stream>>>(pc_W, pcWt, 2048, 256);
  transpose_bf<<<dim3(8, 8, 32),   dim3(32, 8), 0, stream>>>(hp_W, hpWt, 256, 256);
  transpose_bf<<<dim3(128, 8, 1),  dim3(32, 8), 0, stream>>>(alp_W, alpWt, 256, 4096);
  transpose_bf<<<dim3(32, 32, 1),  dim3(32, 8), 0, stream>>>(Wo, WoT, 1024, 1024);
  cvt_x       <<<65536, 256, 0, stream>>>(x, A2);

  gemm_p<0, 1024> <<<dim3(25, 256),  512, 0, stream>>>(A2, W2t, qb, kb, vb, flatb, nullptr, nullptr);
  gemm_bt<1>      <<<dim3(2, 8),     256, 0, stream>>>(flatb, pcWt, 2048, pvtmp, pc_b);
  ln_kernel       <<<1024, 256, 0, stream>>>(pvtmp, ln_g, ln_b, pvb);
  gemm_bt<2>      <<<dim3(2, 8, 32), 256, 0, stream>>>(pvb, hpWt, 256, hvb, hp_b);
  gemm_p<3, 256>  <<<dim3(32, 128),  512, 0, stream>>>(hvb, alpWt, logits, nullptr, nullptr, nullptr, alp_b, pos_b);
  attn_mfma       <<<32768, 64, 0, stream>>>(qb, kb, vb, logits, aout);
  gemm_p<4, 1024> <<<dim3(8, 256),   512, 0, stream>>>(aout, WoT, out, nullptr, nullptr, nullptr, bo, nullptr);
}

// Round 16
// 1046.878 us; speedup vs baseline: 1.2960x; 1.0375x over previous
//
#include <hip/hip_runtime.h>
#include <hip/hip_bf16.h>
#include <cstdint>
#include <cstddef>

typedef __attribute__((ext_vector_type(4))) float f32x4;
typedef __attribute__((ext_vector_type(8))) short short8;
typedef unsigned short u16;
typedef __attribute__((ext_vector_type(8))) unsigned short u16x8;
typedef __attribute__((ext_vector_type(4))) unsigned short u16x4;

// ---------- helpers ----------
__device__ __forceinline__ u16 f2bf(float f) {
  union { float f; unsigned u; } v; v.f = f;
  unsigned r = v.u + 0x7FFFu + ((v.u >> 16) & 1u);
  return (u16)(r >> 16);
}
__device__ __forceinline__ float bf2f(u16 h) {
  union { unsigned u; float f; } v; v.u = ((unsigned)h) << 16;
  return v.f;
}
__device__ __forceinline__ void gload16(const u16* g, const u16* l) {
  __builtin_amdgcn_global_load_lds((const __attribute__((address_space(1))) void*)g,
                                   (__attribute__((address_space(3))) void*)l, 16, 0, 0);
}
__device__ __forceinline__ void fenced_barrier() {
  __builtin_amdgcn_sched_barrier(0);
  __builtin_amdgcn_s_barrier();
  __builtin_amdgcn_sched_barrier(0);
}

// ---------- fused prep: cvt_x (blocks 0..65535) | W2t build (next 3200) | 4 transposes (next 4608) ----------
__global__ __launch_bounds__(256) void prep_all(
    const float* __restrict__ Wq, const float* __restrict__ Wk, const float* __restrict__ Wv,
    const float* __restrict__ tc, const float* __restrict__ pc_W, const float* __restrict__ hp_W,
    const float* __restrict__ alp_W, const float* __restrict__ Wo, const float* __restrict__ x,
    u16* __restrict__ W2t, u16* __restrict__ pcWt, u16* __restrict__ hpWt,
    u16* __restrict__ alpWt, u16* __restrict__ WoT, u16* __restrict__ A2)
{
  __shared__ float t[32][33];
  const int tid = threadIdx.x;
  int bid = blockIdx.x;

  if (bid < 65536) {                      // ---- cvt_x: fp32 -> bf16 linear ----
    size_t i = (size_t)bid * 256 + tid;
    f32x4 v = ((const f32x4*)x)[i];
    u16x4 o;
    #pragma unroll
    for (int j = 0; j < 4; j++) o[j] = f2bf(v[j]);
    ((u16x4*)A2)[i] = o;
    return;
  }
  bid -= 65536;
  const int tx = tid & 31, ty = tid >> 5;

  if (bid < 3200) {                       // ---- W2t = transpose(concat(Wq,Wk,Wv,tc)) [3200][1024] ----
    const int k0 = (bid & 31) * 32, n0 = (bid >> 5) * 32;
    const float* src = nullptr; int col = 0, sw = 0;
    if      (n0 < 1024) { src = Wq; col = n0;        sw = 1024; }
    else if (n0 < 2048) { src = Wk; col = n0 - 1024; sw = 1024; }
    else if (n0 < 3072) { src = Wv; col = n0 - 2048; sw = 1024; }
    else if (n0 < 3104) { src = tc; col = n0 - 3072; sw = 32;   }
    if (src) {
      #pragma unroll
      for (int r = 0; r < 4; r++)
        t[ty + r * 8][tx] = src[(size_t)(k0 + ty + r * 8) * sw + col + tx];
    }
    __syncthreads();
    #pragma unroll
    for (int r = 0; r < 4; r++) {
      int n = n0 + ty + r * 8, k = k0 + tx;
      u16 v = src ? f2bf(t[tx][ty + r * 8]) : (u16)0;
      W2t[(size_t)n * 1024 + k] = v;
    }
    return;
  }
  bid -= 3200;                            // ---- generic fp32 [R][C] -> bf16 transposed [C][R] ----
  const float* src; u16* dst; int R, C, gx, gy, zz = 0;
  if (bid < 512)       { src = pc_W;  dst = pcWt;  R = 2048; C = 256;  gx = bid & 7;   gy = bid >> 3; }
  else if (bid < 2560) { int i = bid - 512;  src = hp_W;  dst = hpWt;  R = 256;  C = 256;
                         gx = i & 7; gy = (i >> 3) & 7; zz = i >> 6; }
  else if (bid < 3584) { int i = bid - 2560; src = alp_W; dst = alpWt; R = 256;  C = 4096;
                         gx = i & 127; gy = i >> 7; }
  else                 { int i = bid - 3584; src = Wo;    dst = WoT;   R = 1024; C = 1024;
                         gx = i & 31; gy = i >> 5; }
  src += (size_t)zz * R * C; dst += (size_t)zz * R * C;
  const int c0 = gx * 32, r0 = gy * 32;
  #pragma unroll
  for (int r = 0; r < 4; r++)
    t[ty + r * 8][tx] = src[(size_t)(r0 + ty + r * 8) * C + c0 + tx];
  __syncthreads();
  #pragma unroll
  for (int r = 0; r < 4; r++)
    dst[(size_t)(c0 + ty + r * 8) * R + r0 + tx] = f2bf(t[tx][ty + r * 8]);
}

// ---------- pipelined GEMM (R15-proven): 256x128 tile, BK=32, 8 waves (4Mx2N), ring-3, 72 KiB ----------
// Unrolled x3 with STATIC ring indices (K compile-time; NT-2 % 3 == 0 for K in {1024, 256}).
// A fold: [128 R][8 chunks of 8 u16]: global row = bm*256 + hb*128 + R, stored chunk = (hb*4+sg) ^ (R&7).
// B fold: [64 R][8 chunks]: global col = bn*128 + hb*64 + R, stored = (hb*4+sg) ^ (R&7).
// Per K-tile t: vmcnt(3); barrier; {8 ds_reads; STG(t+2) (3 gloads); lgkm0; 16 MFMA 16x16x32}.
// MODE 0: QKV+flat scatter   MODE 3: logits (+alp_b+pos_bias, bf16)   MODE 4: final (+bo, f32)
template<int MODE, int K>
__global__ __launch_bounds__(512, 4) void gemm_p(
    const u16* __restrict__ A, const u16* __restrict__ Bt,
    void* __restrict__ o0, void* __restrict__ o1, void* __restrict__ o2, void* __restrict__ o3,
    const float* __restrict__ bias0, const float* __restrict__ bias1)
{
  __shared__ __align__(16) u16 lds[3][12288];   // [buf][ A:0..8191 | B:8192..12287 ] = 72 KiB
  const int tid = threadIdx.x;
  const int wid = tid >> 6, lane = tid & 63;
  const int wm = wid >> 1, wn = wid & 1;        // wave grid 4(M) x 2(N); per-wave out 64x64
  const int g = lane >> 4, l15 = lane & 15;

  // XCD-bijective block swizzle (all grids have nwg%8==0)
  const int GX = gridDim.x;
  const int nwg = GX * (int)gridDim.y;
  const int lin = (int)blockIdx.y * GX + (int)blockIdx.x;
  const int swz = (lin & 7) * (nwg >> 3) + (lin >> 3);
  const int bn = swz % GX, bm = swz / GX;

  // staging lane decomposition: one gload = 8 folded rows; lane -> (row lR, stored chunk lane&7)
  const int lR = lane >> 3;
  const int logi = (lane & 7) ^ lR;
  const int shb = logi >> 2;
  const int sg = logi & 3;

  const u16* pA0 = A + (size_t)(bm * 256 + shb * 128 + (wid * 2 + 0) * 8 + lR) * K + sg * 8;
  const u16* pA1 = A + (size_t)(bm * 256 + shb * 128 + (wid * 2 + 1) * 8 + lR) * K + sg * 8;
  const u16* pB  = Bt + (size_t)(bn * 128 + shb * 64 + wid * 8 + lR) * K + sg * 8;

  const int aRd = ((wm & 1) * 64 + l15) * 64 + ((((wm >> 1) << 2) | g) ^ (l15 & 7)) * 8;
  const int bRd = 8192 + l15 * 64 + ((((wn << 2) | g) ^ (l15 & 7)) * 8);

  f32x4 acc[4][4];
  #pragma unroll
  for (int i = 0; i < 4; i++)
    #pragma unroll
    for (int j = 0; j < 4; j++)
      #pragma unroll
      for (int r = 0; r < 4; r++) acc[i][j][r] = 0.f;

  constexpr int NT = K >> 5;
  static_assert((NT - 2) % 3 == 0, "unroll-3 requires NT-2 divisible by 3");

#define STG(buf, kt) do {                                                   \
    gload16(pA0 + (size_t)(kt) * 32, &lds[buf][(wid * 2 + 0) * 512]);       \
    gload16(pA1 + (size_t)(kt) * 32, &lds[buf][(wid * 2 + 1) * 512]);       \
    gload16(pB  + (size_t)(kt) * 32, &lds[buf][8192 + wid * 512]); } while (0)

#define ITER(T_, RB_, WB_, DO_STG, VM) do {                                 \
    asm volatile("s_waitcnt vmcnt(" #VM ")" ::: "memory");                  \
    fenced_barrier();                                                       \
    short8 af[4], bfr[4];                                                   \
    _Pragma("unroll")                                                       \
    for (int f_ = 0; f_ < 4; f_++)                                          \
      af[f_] = *(const short8*)&lds[RB_][aRd + f_ * 1024];                  \
    _Pragma("unroll")                                                       \
    for (int n_ = 0; n_ < 4; n_++)                                          \
      bfr[n_] = *(const short8*)&lds[RB_][bRd + n_ * 1024];                 \
    if (DO_STG) STG(WB_, (T_) + 2);                                         \
    asm volatile("s_waitcnt lgkmcnt(0)" ::: "memory");                      \
    __builtin_amdgcn_sched_barrier(0);                                      \
    __builtin_amdgcn_s_setprio(1);                                          \
    _Pragma("unroll")                                                       \
    for (int f_ = 0; f_ < 4; f_++)                                          \
      _Pragma("unroll")                                                     \
      for (int n_ = 0; n_ < 4; n_++)                                        \
        acc[f_][n_] = __builtin_amdgcn_mfma_f32_16x16x32_bf16(              \
            af[f_], bfr[n_], acc[f_][n_], 0, 0, 0);                         \
    __builtin_amdgcn_s_setprio(0);                                          \
  } while (0)

  STG(0, 0); STG(1, 1);

  for (int tb = 0; tb < NT - 2; tb += 3) {
    ITER(tb + 0, 0, 2, true, 3);
    ITER(tb + 1, 1, 0, true, 3);
    ITER(tb + 2, 2, 1, true, 3);
  }
  ITER(NT - 2, 0, 0, false, 3);
  ITER(NT - 1, 1, 0, false, 0);
#undef ITER
#undef STG

  const int lr = lane >> 4, lc = lane & 15;
  #pragma unroll
  for (int fm = 0; fm < 4; fm++) {
    #pragma unroll
    for (int fn = 0; fn < 4; fn++) {
      #pragma unroll
      for (int r = 0; r < 4; r++) {
        int gm = bm * 256 + wm * 64 + fm * 16 + lr * 4 + r;
        int gn = bn * 128 + wn * 64 + fn * 16 + lc;
        float val = acc[fm][fn][r];
        if (MODE == 0) {
          int b = gm >> 6, s = gm & 63;
          if (gn < 3072) {
            int which = gn >> 10, hh = (gn >> 5) & 31, d = gn & 31;
            u16* dst = (which == 0) ? (u16*)o0 : (which == 1) ? (u16*)o1 : (u16*)o2;
            dst[(((size_t)b * 32 + hh) * 64 + s) * 32 + d] = f2bf(val);
          } else if (gn < 3104) {
            ((u16*)o3)[(size_t)b * 2048 + s * 32 + (gn - 3072)] = f2bf(val);
          }
        } else if (MODE == 3) {
          ((u16*)o0)[(size_t)gm * 4096 + gn] = f2bf(val + bias0[gn] + bias1[(gm & 31) * 4096 + gn]);
        } else {
          ((float*)o0)[(size_t)gm * 1024 + gn] = val + bias0[gn];
        }
      }
    }
  }
}

// ---------- small GEMM: 128x128 tile. MODE 1: K-split partial (z = K-chunk of 256, f32 partials)
//            MODE 2: per-head hv (+bias, bf16), z = head ----------
template<int MODE>
__global__ __launch_bounds__(256) void gemm_bt(
    const u16* __restrict__ A, const u16* __restrict__ Bt, int kstride, int klen,
    void* __restrict__ o0, const float* __restrict__ bias0)
{
  __shared__ __align__(16) u16 lA[128 * 32];
  __shared__ __align__(16) u16 lB[128 * 32];
  const int tid = threadIdx.x;
  const int wid = tid >> 6, lane = tid & 63;
  const int wm = wid >> 1, wn = wid & 1;
  const int bn = blockIdx.x, bm = blockIdx.y, z = blockIdx.z;
  if (MODE == 2) Bt += (size_t)z * 256 * 256;
  const int kbeg = (MODE == 1) ? z * 256 : 0;
  float* opart = (MODE == 1) ? ((float*)o0) + (size_t)z * 1024 * 256 : (float*)o0;

  f32x4 acc[4][4];
  #pragma unroll
  for (int i = 0; i < 4; i++)
    #pragma unroll
    for (int j = 0; j < 4; j++)
      #pragma unroll
      for (int r = 0; r < 4; r++) acc[i][j][r] = 0.f;

  const u16* Arow = A + (size_t)(bm * 128) * kstride + kbeg;
  const u16* Brow = Bt + (size_t)(bn * 128) * kstride + kbeg;

  for (int k0 = 0; k0 < klen; k0 += 32) {
    #pragma unroll
    for (int i = 0; i < 2; i++) {
      int c = wid * 128 + i * 64 + lane;
      int row = c >> 2, col = (c & 3) * 8;
      gload16(Arow + (size_t)row * kstride + k0 + col, &lA[(wid * 128 + i * 64) * 8]);
      gload16(Brow + (size_t)row * kstride + k0 + col, &lB[(wid * 128 + i * 64) * 8]);
    }
    __syncthreads();
    short8 af[4], bfr[4];
    #pragma unroll
    for (int f = 0; f < 4; f++) {
      af[f]  = *(const short8*)&lA[(wm * 64 + f * 16 + (lane & 15)) * 32 + (lane >> 4) * 8];
      bfr[f] = *(const short8*)&lB[(wn * 64 + f * 16 + (lane & 15)) * 32 + (lane >> 4) * 8];
    }
    #pragma unroll
    for (int fm = 0; fm < 4; fm++)
      #pragma unroll
      for (int fn = 0; fn < 4; fn++)
        acc[fm][fn] = __builtin_amdgcn_mfma_f32_16x16x32_bf16(af[fm], bfr[fn], acc[fm][fn], 0, 0, 0);
    __syncthreads();
  }

  const int lr = lane >> 4, lc = lane & 15;
  #pragma unroll
  for (int fm = 0; fm < 4; fm++) {
    #pragma unroll
    for (int fn = 0; fn < 4; fn++) {
      #pragma unroll
      for (int r = 0; r < 4; r++) {
        int gm = bm * 128 + wm * 64 + fm * 16 + lr * 4 + r;
        int gn = bn * 128 + wn * 64 + fn * 16 + lc;
        float val = acc[fm][fn][r];
        if (MODE == 1) {
          opart[(size_t)gm * 256 + gn] = val;
        } else if (MODE == 2) {
          ((u16*)o0)[((size_t)gm * 32 + z) * 256 + gn] = f2bf(val + bias0[z * 256 + gn]);
        }
      }
    }
  }
}

// ---------- LayerNorm over 256 cols: sum 8 K-partials + pc_b, relu, then LN ----------
__global__ __launch_bounds__(256) void ln_kernel(
    const float* __restrict__ pv8, const float* __restrict__ pcb,
    const float* __restrict__ g, const float* __restrict__ b2, u16* __restrict__ out)
{
  __shared__ float red[256];
  const int bi = blockIdx.x, t = threadIdx.x;
  float v = 0.f;
  #pragma unroll
  for (int z = 0; z < 8; z++) v += pv8[(size_t)z * 262144 + (size_t)bi * 256 + t];
  v += pcb[t];
  v = v > 0.f ? v : 0.f;
  red[t] = v; __syncthreads();
  #pragma unroll
  for (int o = 128; o > 0; o >>= 1) { if (t < o) red[t] += red[t + o]; __syncthreads(); }
  float mu = red[0] * (1.f / 256.f);
  __syncthreads();
  float dv = v - mu;
  red[t] = dv * dv; __syncthreads();
  #pragma unroll
  for (int o = 128; o > 0; o >>= 1) { if (t < o) red[t] += red[t + o]; __syncthreads(); }
  float var = red[0] * (1.f / 256.f);
  float rs = rsqrtf(var + 1e-5f);
  out[(size_t)bi * 256 + t] = f2bf(dv * rs * g[t] + b2[t]);
}

// ---------- attention core (R15-proven): one wave per (b,h) ----------
__global__ __launch_bounds__(64) void attn_mfma(
    const u16* __restrict__ qb, const u16* __restrict__ kb, const u16* __restrict__ vb,
    const u16* __restrict__ lg, u16* __restrict__ aout)
{
  __shared__ __align__(16) u16 vT[32 * 64];
  __shared__ __align__(16) u16 Pl[64 * 64];
  const int bid = blockIdx.x;
  const int lane = threadIdx.x;
  const int g = lane >> 4, l15 = lane & 15;
  const size_t base = (size_t)bid * 2048;

  {
    const u16* vrow = vb + base + lane * 32;
    u16x8 vv[4];
    #pragma unroll
    for (int c = 0; c < 4; c++) vv[c] = *(const u16x8*)(vrow + c * 8);
    #pragma unroll
    for (int d = 0; d < 32; d++)
      vT[d * 64 + (lane ^ ((d & 7) << 3))] = vv[d >> 3][d & 7];
  }

  short8 qf[4], kf[4];
  #pragma unroll
  for (int t = 0; t < 4; t++) {
    qf[t] = *(const short8*)(qb + base + (size_t)(t * 16 + l15) * 32 + g * 8);
    kf[t] = *(const short8*)(kb + base + (size_t)(t * 16 + l15) * 32 + g * 8);
  }

  f32x4 s[4][4];
  #pragma unroll
  for (int tm = 0; tm < 4; tm++)
    #pragma unroll
    for (int tn = 0; tn < 4; tn++)
      #pragma unroll
      for (int r = 0; r < 4; r++) s[tm][tn][r] = 0.f;
  #pragma unroll
  for (int tm = 0; tm < 4; tm++)
    #pragma unroll
    for (int tn = 0; tn < 4; tn++)
      s[tm][tn] = __builtin_amdgcn_mfma_f32_16x16x32_bf16(kf[tm], qf[tn], s[tm][tn], 0, 0, 0);

  const float scale = 0.17677669529663687f;
  float inv4[4];
  const u16* lbase = lg + (size_t)bid * 4096;
  #pragma unroll
  for (int tn = 0; tn < 4; tn++) {
    const int q = tn * 16 + l15;
    float mx = -1e30f;
    #pragma unroll
    for (int tm = 0; tm < 4; tm++) {
      u16x4 u = *(const u16x4*)(lbase + (size_t)q * 64 + tm * 16 + g * 4);
      #pragma unroll
      for (int r = 0; r < 4; r++) {
        s[tm][tn][r] = s[tm][tn][r] * scale + bf2f(u[r]);
        mx = fmaxf(mx, s[tm][tn][r]);
      }
    }
    mx = fmaxf(mx, __shfl_xor(mx, 16));
    mx = fmaxf(mx, __shfl_xor(mx, 32));
    float sm = 0.f;
    #pragma unroll
    for (int tm = 0; tm < 4; tm++)
      #pragma unroll
      for (int r = 0; r < 4; r++) {
        float e = __expf(s[tm][tn][r] - mx);
        s[tm][tn][r] = e;
        sm += e;
      }
    sm += __shfl_xor(sm, 16);
    sm += __shfl_xor(sm, 32);
    inv4[tn] = 1.f / sm;
    #pragma unroll
    for (int tm = 0; tm < 4; tm++) {
      u16x4 p;
      #pragma unroll
      for (int r = 0; r < 4; r++) p[r] = f2bf(s[tm][tn][r]);
      *(u16x4*)&Pl[q * 64 + ((tm * 16 + g * 4) ^ ((q & 7) << 3))] = p;
    }
  }
  __syncthreads();

  f32x4 o[2][4];
  #pragma unroll
  for (int md = 0; md < 2; md++)
    #pragma unroll
    for (int tn = 0; tn < 4; tn++)
      #pragma unroll
      for (int r = 0; r < 4; r++) o[md][tn][r] = 0.f;
  #pragma unroll
  for (int ks = 0; ks < 2; ks++) {
    short8 vf2[2], pf[4];
    #pragma unroll
    for (int md = 0; md < 2; md++)
      vf2[md] = *(const short8*)&vT[(md * 16 + l15) * 64 + ((ks * 32 + g * 8) ^ ((l15 & 7) << 3))];
    #pragma unroll
    for (int tn = 0; tn < 4; tn++)
      pf[tn] = *(const short8*)&Pl[(tn * 16 + l15) * 64 + ((ks * 32 + g * 8) ^ ((l15 & 7) << 3))];
    #pragma unroll
    for (int md = 0; md < 2; md++)
      #pragma unroll
      for (int tn = 0; tn < 4; tn++)
        o[md][tn] = __builtin_amdgcn_mfma_f32_16x16x32_bf16(vf2[md], pf[tn], o[md][tn], 0, 0, 0);
  }

  const int b = bid >> 5, h = bid & 31;
  #pragma unroll
  for (int md = 0; md < 2; md++) {
    #pragma unroll
    for (int tn = 0; tn < 4; tn++) {
      const int q = tn * 16 + l15, d0 = md * 16 + g * 4;
      u16x4 u;
      #pragma unroll
      for (int r = 0; r < 4; r++) u[r] = f2bf(o[md][tn][r] * inv4[tn]);
      *(u16x4*)(aout + ((size_t)(b * 64 + q)) * 1024 + h * 32 + d0) = u;
    }
  }
}

// ---------- launch ----------
extern "C" void kernel_launch(void* const* d_in, const int* in_sizes, int n_in,
                              void* d_out, int out_size, void* d_ws, size_t ws_size,
                              hipStream_t stream) {
  const float* x       = (const float*)d_in[0];
  const float* Wq      = (const float*)d_in[1];
  const float* Wk      = (const float*)d_in[2];
  const float* Wv      = (const float*)d_in[3];
  const float* Wo      = (const float*)d_in[4];
  const float* bo      = (const float*)d_in[5];
  const float* pos_b   = (const float*)d_in[6];
  const float* tc_W    = (const float*)d_in[7];
  const float* pc_W    = (const float*)d_in[8];
  const float* pc_b    = (const float*)d_in[9];
  const float* ln_g    = (const float*)d_in[10];
  const float* ln_b    = (const float*)d_in[11];
  const float* hp_W    = (const float*)d_in[12];
  const float* hp_b    = (const float*)d_in[13];
  const float* alp_W   = (const float*)d_in[14];
  const float* alp_b   = (const float*)d_in[15];
  float* out = (float*)d_out;

  char* w = (char*)d_ws;
  u16* A2     = (u16*)w;              // 134 MB bf16 x, dead after gemm_p<0>
  u16* logits = (u16*)w;              w += 268435456;   // logits aliases A2 region
  u16* qb     = (u16*)w;              w += 134217728;
  u16* kb     = (u16*)w;              w += 134217728;
  u16* vb     = (u16*)w;              w += 134217728;
  u16* aout   = (u16*)w;              w += 134217728;
  u16* W2t    = (u16*)w;              w += (size_t)3200 * 1024 * 2;
  u16* pcWt   = (u16*)w;              w += (size_t)256 * 2048 * 2;
  u16* hpWt   = (u16*)w;              w += (size_t)32 * 256 * 256 * 2;
  u16* alpWt  = (u16*)w;              w += (size_t)4096 * 256 * 2;
  u16* WoT    = (u16*)w;              w += (size_t)1024 * 1024 * 2;
  u16* flatb  = (u16*)w;              w += (size_t)1024 * 2048 * 2;
  float* pv8  = (float*)w;            w += (size_t)8 * 1024 * 256 * 4;
  u16* pvb    = (u16*)w;              w += (size_t)1024 * 256 * 2;
  u16* hvb    = (u16*)w;              w += (size_t)32768 * 256 * 2;

  prep_all<<<73344, 256, 0, stream>>>(Wq, Wk, Wv, tc_W, pc_W, hp_W, alp_W, Wo, x,
                                      W2t, pcWt, hpWt, alpWt, WoT, A2);

  gemm_p<0, 1024> <<<dim3(25, 256),  512, 0, stream>>>(A2, W2t, qb, kb, vb, flatb, nullptr, nullptr);
  gemm_bt<1>      <<<dim3(2, 8, 8),  256, 0, stream>>>(flatb, pcWt, 2048, 256, pv8, nullptr);
  ln_kernel       <<<1024, 256, 0, stream>>>(pv8, pc_b, ln_g, ln_b, pvb);
  gemm_bt<2>      <<<dim3(2, 8, 32), 256, 0, stream>>>(pvb, hpWt, 256, 256, hvb, hp_b);
  gemm_p<3, 256>  <<<dim3(32, 128),  512, 0, stream>>>(hvb, alpWt, logits, nullptr, nullptr, nullptr, alp_b, pos_b);
  attn_mfma       <<<32768, 64, 0, stream>>>(qb, kb, vb, logits, aout);
  gemm_p<4, 1024> <<<dim3(8, 256),   512, 0, stream>>>(aout, WoT, out, nullptr, nullptr, nullptr, bo, nullptr);
}